// Round 1
// baseline (5438.335 us; speedup 1.0000x reference)
//
#include <hip/hip_runtime.h>
#include <hip/hip_bf16.h>
#include <math.h>
#include <stddef.h>

// ---------------------------------------------------------------------------
// Transformer layer, fp32 baseline for MI355X.
//   B=2 T=2048 C=1024 H=16 HS=64 FF=4096.  M = B*T = 4096.
// Structure:
//   1. ln_kernel:        h = LN(x, ln1_w)
//   2. gemm128<1,0> x3:  q/k/v = h @ W{q,k,v} + b   (stored [B,T,H*HS])
//   3. colstats_kernel:  per-COLUMN softmax stats (softmax is over query axis i!)
//   4. pv_kernel:        att[i] = sum_{j<=i} exp(s_ij - m_j)*rl_j * v[j]
//   5. gemm128<0,2>:     x1 = att @ Wo + bo + x
//   6. ln_kernel:        h2 = LN(x1, ln2_w)
//   7. gemm128<0,1>:     ffmid = relu(h2 @ W1 + b1)
//   8. gemm128<0,2>:     out = ffmid @ W2 + b2 + x1
// ---------------------------------------------------------------------------

constexpr int Bn = 2, Tn = 2048, Cn = 1024, Hn = 16, HSn = 64, FFn = 4096;
constexpr int Mn = Bn * Tn;            // 4096 rows
constexpr float EPSf  = 1e-5f;
constexpr float SCALE = 0.125f;        // HS^-0.5

#define DEVINL __device__ __forceinline__

// ---------------- LayerNorm: one block per row (C=1024, 256 thr x float4) ---
__global__ __launch_bounds__(256)
void ln_kernel(const float* __restrict__ x, const float* __restrict__ w,
               float* __restrict__ out) {
  const int row = blockIdx.x;
  const int tid = threadIdx.x;
  const float4 v = ((const float4*)(x + (size_t)row * Cn))[tid];
  float s  = v.x + v.y + v.z + v.w;
  float ss = v.x*v.x + v.y*v.y + v.z*v.z + v.w*v.w;
#pragma unroll
  for (int o = 32; o > 0; o >>= 1) {
    s  += __shfl_xor(s,  o);
    ss += __shfl_xor(ss, o);
  }
  __shared__ float red[8];
  const int wv = tid >> 6;
  if ((tid & 63) == 0) { red[wv] = s; red[wv + 4] = ss; }
  __syncthreads();
  s  = red[0] + red[1] + red[2] + red[3];
  ss = red[4] + red[5] + red[6] + red[7];
  const float mu   = s * (1.0f / Cn);
  const float var  = ss * (1.0f / Cn) - mu * mu;
  const float rstd = rsqrtf(var + EPSf);
  const float4 wv4 = ((const float4*)w)[tid];
  float4 o;
  o.x = (v.x - mu) * rstd * wv4.x;
  o.y = (v.y - mu) * rstd * wv4.y;
  o.z = (v.z - mu) * rstd * wv4.z;
  o.w = (v.w - mu) * rstd * wv4.w;
  ((float4*)(out + (size_t)row * Cn))[tid] = o;
}

// ---------------- Generic fp32 GEMM, 128x128x16 tile, 8x8 per thread -------
// BMODE 0: B row-major [K][N].  BMODE 1: qkv weights [H][C][HS], n = h*64+d.
// EPI 0: +bias.  EPI 1: +bias, relu.  EPI 2: +bias +res[m*N+n].
template <int BMODE, int EPI>
__global__ __launch_bounds__(256)
void gemm128(const float* __restrict__ A, const float* __restrict__ Bm,
             const float* __restrict__ bias, const float* __restrict__ res,
             float* __restrict__ out, int M, int N, int K) {
  __shared__ float As[16][132];   // [k][m], padded
  __shared__ float Bs[16][132];   // [k][n], padded
  const int tid = threadIdx.x;
  const int m0 = blockIdx.y * 128, n0 = blockIdx.x * 128;
  const int tx = tid & 15, ty = tid >> 4;
  const int a_m = tid >> 1;            // 0..127
  const int a_k = (tid & 1) * 8;       // 0 or 8
  const int b_k = tid >> 4;            // 0..15
  const int b_n = (tid & 15) * 4;      // 0..60
  float acc[8][8] = {};
  const float* Ap = A + (size_t)(m0 + a_m) * K + a_k;
  for (int k0 = 0; k0 < K; k0 += 16) {
    const float4 av0 = *(const float4*)(Ap + k0);
    const float4 av1 = *(const float4*)(Ap + k0 + 4);
    float4 bv0, bv1;
    if (BMODE == 0) {
      const float* Bp = Bm + (size_t)(k0 + b_k) * N + n0;
      bv0 = *(const float4*)(Bp + b_n);
      bv1 = *(const float4*)(Bp + b_n + 64);
    } else {
      const int n_g0 = n0 + b_n, n_g1 = n0 + b_n + 64;
      bv0 = *(const float4*)(Bm + (size_t)(n_g0 >> 6) * (Cn * HSn) +
                             (size_t)(k0 + b_k) * HSn + (n_g0 & 63));
      bv1 = *(const float4*)(Bm + (size_t)(n_g1 >> 6) * (Cn * HSn) +
                             (size_t)(k0 + b_k) * HSn + (n_g1 & 63));
    }
    __syncthreads();   // previous compute done before overwriting LDS
    As[a_k + 0][a_m] = av0.x;
    As[a_k + 1][a_m] = av0.y;
    As[a_k + 2][a_m] = av0.z;
    As[a_k + 3][a_m] = av0.w;
    As[a_k + 4][a_m] = av1.x;
    As[a_k + 5][a_m] = av1.y;
    As[a_k + 6][a_m] = av1.z;
    As[a_k + 7][a_m] = av1.w;
    *(float4*)&Bs[b_k][b_n]      = bv0;
    *(float4*)&Bs[b_k][b_n + 64] = bv1;
    __syncthreads();
#pragma unroll
    for (int kk = 0; kk < 16; kk++) {
      float a[8], b[8];
      *(float4*)&a[0] = *(const float4*)&As[kk][ty * 8];
      *(float4*)&a[4] = *(const float4*)&As[kk][ty * 8 + 4];
      *(float4*)&b[0] = *(const float4*)&Bs[kk][tx * 8];
      *(float4*)&b[4] = *(const float4*)&Bs[kk][tx * 8 + 4];
#pragma unroll
      for (int i = 0; i < 8; i++)
#pragma unroll
        for (int j = 0; j < 8; j++)
          acc[i][j] = fmaf(a[i], b[j], acc[i][j]);
    }
  }
#pragma unroll
  for (int i = 0; i < 8; i++) {
    const int m = m0 + ty * 8 + i;
#pragma unroll
    for (int j4 = 0; j4 < 2; j4++) {
      const int nb = n0 + tx * 8 + j4 * 4;
      const float4 bb = *(const float4*)(bias + nb);
      float4 o;
      o.x = acc[i][j4 * 4 + 0] + bb.x;
      o.y = acc[i][j4 * 4 + 1] + bb.y;
      o.z = acc[i][j4 * 4 + 2] + bb.z;
      o.w = acc[i][j4 * 4 + 3] + bb.w;
      if (EPI == 1) {
        o.x = fmaxf(o.x, 0.f); o.y = fmaxf(o.y, 0.f);
        o.z = fmaxf(o.z, 0.f); o.w = fmaxf(o.w, 0.f);
      }
      if (EPI == 2) {
        const float4 r = *(const float4*)(res + (size_t)m * N + nb);
        o.x += r.x; o.y += r.y; o.z += r.z; o.w += r.w;
      }
      *(float4*)(out + (size_t)m * N + nb) = o;
    }
  }
}

// ---- stage a 64x64 fp32 tile (row stride Cn in global) into LDS [64][68] ---
DEVINL void stage64(float dst[64][68], const float* __restrict__ src, int tid) {
#pragma unroll
  for (int s2 = 0; s2 < 4; s2++) {
    const int f = tid + 256 * s2;       // 0..1023
    const int row = f >> 4;
    const int c4 = (f & 15) * 4;
    *(float4*)&dst[row][c4] = *(const float4*)(src + (size_t)row * Cn + c4);
  }
}

// ---------------- Pass A: column softmax stats (softmax over query axis i) --
// grid (T/64, B*H).  Column tile j0..j0+63; online max/sum over i >= j.
__global__ __launch_bounds__(256)
void colstats_kernel(const float* __restrict__ q, const float* __restrict__ k,
                     float* __restrict__ mbuf, float* __restrict__ rlbuf) {
  __shared__ float ks[64][68];
  __shared__ float qs[64][68];
  __shared__ float ms[4][64], ls[4][64];
  const int j0 = blockIdx.x * 64;
  const int bh = blockIdx.y;
  const int b = bh >> 4, h = bh & 15;
  const int tid = threadIdx.x;
  const int lane = tid & 63, grp = tid >> 6;

  stage64(ks, k + ((size_t)(b * Tn + j0)) * Cn + h * HSn, tid);
  __syncthreads();
  float kr[64];
#pragma unroll
  for (int f = 0; f < 16; f++) {
    const float4 t4 = *(const float4*)&ks[lane][f * 4];
    kr[f*4+0] = t4.x; kr[f*4+1] = t4.y; kr[f*4+2] = t4.z; kr[f*4+3] = t4.w;
  }
  float mloc = -1e30f, lloc = 0.f;
  for (int i0 = j0; i0 < Tn; i0 += 64) {
    __syncthreads();
    stage64(qs, q + ((size_t)(b * Tn + i0)) * Cn + h * HSn, tid);
    __syncthreads();
#pragma unroll
    for (int r = 0; r < 16; r++) {
      const int ii = grp * 16 + r;
      float s = 0.f;
#pragma unroll
      for (int f = 0; f < 16; f++) {
        const float4 qv = *(const float4*)&qs[ii][f * 4];
        s = fmaf(qv.x, kr[f*4+0], s);
        s = fmaf(qv.y, kr[f*4+1], s);
        s = fmaf(qv.z, kr[f*4+2], s);
        s = fmaf(qv.w, kr[f*4+3], s);
      }
      s *= SCALE;
      if (i0 + ii >= j0 + lane) {        // causal: valid rows are i >= j
        const float mn = fmaxf(mloc, s);
        lloc = lloc * __expf(mloc - mn) + __expf(s - mn);
        mloc = mn;
      }
    }
  }
  ms[grp][lane] = mloc;
  ls[grp][lane] = lloc;
  __syncthreads();
  if (tid < 64) {
    const float m0_ = ms[0][tid], m1 = ms[1][tid], m2 = ms[2][tid], m3 = ms[3][tid];
    const float mall = fmaxf(fmaxf(m0_, m1), fmaxf(m2, m3));
    const float l = ls[0][tid] * __expf(m0_ - mall) + ls[1][tid] * __expf(m1 - mall)
                  + ls[2][tid] * __expf(m2 - mall) + ls[3][tid] * __expf(m3 - mall);
    mbuf[(size_t)bh * Tn + j0 + tid]  = mall;
    rlbuf[(size_t)bh * Tn + j0 + tid] = 1.0f / l;
  }
}

// ---------------- Pass B: att[i] = sum_{j<=i} exp(s-m_j)*rl_j * v[j] --------
// grid (T/64, B*H).  Row tile i0..i0+63; loop over key tiles j0 <= i0.
__global__ __launch_bounds__(256)
void pv_kernel(const float* __restrict__ q, const float* __restrict__ k,
               const float* __restrict__ v, const float* __restrict__ mbuf,
               const float* __restrict__ rlbuf, float* __restrict__ att) {
  __shared__ float qs[64][68];
  __shared__ float ks[64][68];
  __shared__ float ps[64][68];
  __shared__ float mj[64], rlj[64];
  const int i0 = blockIdx.x * 64;
  const int bh = blockIdx.y;
  const int b = bh >> 4, h = bh & 15;
  const int tid = threadIdx.x;
  const int lane = tid & 63, grp = tid >> 6;

  stage64(qs, q + ((size_t)(b * Tn + i0)) * Cn + h * HSn, tid);
  float acc[16] = {};
  float kr[64];
  for (int j0 = 0; j0 <= i0; j0 += 64) {
    __syncthreads();   // prev iter done with ks/ps (also publishes qs on iter 0)
    stage64(ks, k + ((size_t)(b * Tn + j0)) * Cn + h * HSn, tid);
    if (tid < 64) {
      mj[tid]  = mbuf[(size_t)bh * Tn + j0 + tid];
      rlj[tid] = rlbuf[(size_t)bh * Tn + j0 + tid];
    }
    __syncthreads();
    // --- s phase: thread = column jj (=lane), 16 rows; k row in registers ---
#pragma unroll
    for (int f = 0; f < 16; f++) {
      const float4 t4 = *(const float4*)&ks[lane][f * 4];
      kr[f*4+0] = t4.x; kr[f*4+1] = t4.y; kr[f*4+2] = t4.z; kr[f*4+3] = t4.w;
    }
    const float mjl = mj[lane], rjl = rlj[lane];
#pragma unroll
    for (int r = 0; r < 16; r++) {
      const int ii = grp * 16 + r;
      float s = 0.f;
#pragma unroll
      for (int f = 0; f < 16; f++) {
        const float4 qv = *(const float4*)&qs[ii][f * 4];
        s = fmaf(qv.x, kr[f*4+0], s);
        s = fmaf(qv.y, kr[f*4+1], s);
        s = fmaf(qv.z, kr[f*4+2], s);
        s = fmaf(qv.w, kr[f*4+3], s);
      }
      s *= SCALE;
      float p = 0.f;
      if (i0 + ii >= j0 + lane) p = __expf(s - mjl) * rjl;
      ps[ii][lane] = p;
    }
    __syncthreads();
    // --- PV phase: thread = output column d (=lane); v column in registers ---
    const float* vp = v + ((size_t)(b * Tn + j0)) * Cn + h * HSn + lane;
#pragma unroll
    for (int jj = 0; jj < 64; jj++) kr[jj] = vp[(size_t)jj * Cn];
#pragma unroll
    for (int r = 0; r < 16; r++) {
      const int ii = grp * 16 + r;
      float sacc = acc[r];
#pragma unroll
      for (int f = 0; f < 16; f++) {
        const float4 pv4 = *(const float4*)&ps[ii][f * 4];
        sacc = fmaf(pv4.x, kr[f*4+0], sacc);
        sacc = fmaf(pv4.y, kr[f*4+1], sacc);
        sacc = fmaf(pv4.z, kr[f*4+2], sacc);
        sacc = fmaf(pv4.w, kr[f*4+3], sacc);
      }
      acc[r] = sacc;
    }
  }
  float* ap = att + ((size_t)(b * Tn + i0)) * Cn + h * HSn + lane;
#pragma unroll
  for (int r = 0; r < 16; r++) ap[(size_t)(grp * 16 + r) * Cn] = acc[r];
}

// ---------------------------------------------------------------------------
extern "C" void kernel_launch(void* const* d_in, const int* in_sizes, int n_in,
                              void* d_out, int out_size, void* d_ws, size_t ws_size,
                              hipStream_t stream) {
  const float* x    = (const float*)d_in[0];
  const float* ln1w = (const float*)d_in[1];
  const float* Wq   = (const float*)d_in[2];
  const float* bq   = (const float*)d_in[3];
  const float* Wk   = (const float*)d_in[4];
  const float* bk   = (const float*)d_in[5];
  const float* Wv   = (const float*)d_in[6];
  const float* bv   = (const float*)d_in[7];
  const float* Wo   = (const float*)d_in[8];
  const float* bo   = (const float*)d_in[9];
  const float* ln2w = (const float*)d_in[10];
  const float* W1   = (const float*)d_in[11];
  const float* b1   = (const float*)d_in[12];
  const float* W2   = (const float*)d_in[13];
  const float* b2   = (const float*)d_in[14];
  float* out = (float*)d_out;

  float* ws = (float*)d_ws;
  const size_t MC = (size_t)Mn * Cn;          // 4M floats
  float* h     = ws;                          // [M,C]   (reused as h2)
  float* qb    = ws + 1 * MC;                 // [M,H*HS]
  float* kb    = ws + 2 * MC;
  float* vb    = ws + 3 * MC;
  float* attb  = ws + 4 * MC;                 // [M,H*HS]
  float* x1    = ws + 5 * MC;                 // [M,C]
  float* mstat = ws + 6 * MC;                 // [B*H*T]
  float* rlst  = mstat + (size_t)Bn * Hn * Tn;
  float* ffmid = qb;                          // reuse q/k/v/att region: 16M floats

  // 1. LN1
  ln_kernel<<<Mn, 256, 0, stream>>>(x, ln1w, h);
  // 2. QKV projections  (M=4096, N=1024, K=1024)
  gemm128<1, 0><<<dim3(8, 32), 256, 0, stream>>>(h, Wq, bq, nullptr, qb, Mn, Cn, Cn);
  gemm128<1, 0><<<dim3(8, 32), 256, 0, stream>>>(h, Wk, bk, nullptr, kb, Mn, Cn, Cn);
  gemm128<1, 0><<<dim3(8, 32), 256, 0, stream>>>(h, Wv, bv, nullptr, vb, Mn, Cn, Cn);
  // 3. column softmax stats
  colstats_kernel<<<dim3(Tn / 64, Bn * Hn), 256, 0, stream>>>(qb, kb, mstat, rlst);
  // 4. PV
  pv_kernel<<<dim3(Tn / 64, Bn * Hn), 256, 0, stream>>>(qb, kb, vb, mstat, rlst, attb);
  // 5. output projection + residual -> x1
  gemm128<0, 2><<<dim3(8, 32), 256, 0, stream>>>(attb, Wo, bo, x, x1, Mn, Cn, Cn);
  // 6. LN2
  ln_kernel<<<Mn, 256, 0, stream>>>(x1, ln2w, h);
  // 7. FFN1 + relu  (N=4096)
  gemm128<0, 1><<<dim3(32, 32), 256, 0, stream>>>(h, W1, b1, nullptr, ffmid, Mn, FFn, Cn);
  // 8. FFN2 + bias + residual -> out  (K=4096)
  gemm128<0, 2><<<dim3(8, 32), 256, 0, stream>>>(ffmid, W2, b2, x1, out, Mn, Cn, FFn);
}

// Round 3
// 479.575 us; speedup vs baseline: 11.3399x; 11.3399x over previous
//
#include <hip/hip_runtime.h>
#include <hip/hip_bf16.h>
#include <stddef.h>
#include <stdint.h>

// ---------------------------------------------------------------------------
// bf16-MFMA transformer layer. B=2 T=2048 C=1024 H=16 HS=64 FF=4096, M=4096.
//  transpose_cvt: fp32 weights -> bf16 B^T [N][K]
//  ln_bf16:       LN -> bf16
//  gemm_bf16:     128x128xBK64 MFMA, gload_lds(16B) + XOR-swizzled LDS
//  colstats_mfma: per-COLUMN softmax stats (softmax over query axis i)
//  pv_mfma:       att[i] = sum_{j<=i} exp2(s2_ij - m2_j)*rl_j * v[j]
// ---------------------------------------------------------------------------

constexpr int Bn = 2, Tn = 2048, Cn = 1024, Hn = 16, HSn = 64, FFn = 4096;
constexpr int Mn = Bn * Tn;
constexpr float EPSf = 1e-5f;
constexpr float S2 = 0.125f * 1.44269504088896340736f;  // HS^-0.5 * log2(e)

using short8 = __attribute__((ext_vector_type(8))) short;
using f32x4  = __attribute__((ext_vector_type(4))) float;
using s16x4  = __attribute__((ext_vector_type(4))) short;

#define DEVINL __device__ __forceinline__

DEVINL unsigned short f2bf(float f) {          // fp32 -> bf16 bits, RNE
  unsigned int u = __float_as_uint(f);
  u += 0x7fffu + ((u >> 16) & 1u);
  return (unsigned short)(u >> 16);
}

#define GLDS16(g, l) __builtin_amdgcn_global_load_lds(                        \
    (const __attribute__((address_space(1))) void*)(g),                       \
    (__attribute__((address_space(3))) void*)(l), 16, 0, 0)

// ---------------- transpose + fp32->bf16:  in [R][S] -> out [S][R] ---------
__global__ __launch_bounds__(256)
void transpose_cvt(const float* __restrict__ in, unsigned short* __restrict__ out,
                   int R, int S, long zin, long zout) {
  __shared__ float tile[32][33];
  const int c0 = blockIdx.x * 32;          // S dim
  const int r0 = blockIdx.y * 32;          // R dim
  in  += (size_t)blockIdx.z * zin;
  out += (size_t)blockIdx.z * zout;
  const int tid = threadIdx.x;
#pragma unroll
  for (int j = 0; j < 4; ++j) {
    const int f = tid + j * 256;
    tile[f >> 5][f & 31] = in[(size_t)(r0 + (f >> 5)) * S + c0 + (f & 31)];
  }
  __syncthreads();
#pragma unroll
  for (int j = 0; j < 4; ++j) {
    const int f = tid + j * 256;
    const int sr = f >> 5, rc = f & 31;
    out[(size_t)(c0 + sr) * R + r0 + rc] = f2bf(tile[rc][sr]);
  }
}

// ---------------- LayerNorm -> bf16 ----------------------------------------
__global__ __launch_bounds__(256)
void ln_bf16(const float* __restrict__ x, const float* __restrict__ w,
             unsigned short* __restrict__ out) {
  const int row = blockIdx.x, tid = threadIdx.x;
  const float4 v = ((const float4*)(x + (size_t)row * Cn))[tid];
  float s  = v.x + v.y + v.z + v.w;
  float ss = v.x*v.x + v.y*v.y + v.z*v.z + v.w*v.w;
#pragma unroll
  for (int o = 32; o > 0; o >>= 1) { s += __shfl_xor(s, o); ss += __shfl_xor(ss, o); }
  __shared__ float red[8];
  if ((tid & 63) == 0) { red[tid >> 6] = s; red[(tid >> 6) + 4] = ss; }
  __syncthreads();
  s  = red[0] + red[1] + red[2] + red[3];
  ss = red[4] + red[5] + red[6] + red[7];
  const float mu   = s * (1.0f / Cn);
  const float rstd = rsqrtf(ss * (1.0f / Cn) - mu * mu + EPSf);
  const float4 wv = ((const float4*)w)[tid];
  s16x4 o;
  o[0] = (short)f2bf((v.x - mu) * rstd * wv.x);
  o[1] = (short)f2bf((v.y - mu) * rstd * wv.y);
  o[2] = (short)f2bf((v.z - mu) * rstd * wv.z);
  o[3] = (short)f2bf((v.w - mu) * rstd * wv.w);
  ((s16x4*)(out + (size_t)row * Cn))[tid] = o;
}

// ---------------- bf16 MFMA GEMM: C[M,N] = A[M,K] * Bt[N,K]^T + bias --------
// EPI: 0 none, 1 relu, 2 +res(fp32).  OMODE: 0 fp32 out, 1 bf16 out,
// 2 transposed bf16 out (V): vT[(m/2048)*1024 + n][m%2048].
template <int EPI, int OMODE>
__global__ __launch_bounds__(256)
void gemm_bf16(const unsigned short* __restrict__ A,
               const unsigned short* __restrict__ Bt,
               const float* __restrict__ bias, const float* __restrict__ res,
               void* __restrict__ outp, int M, int N, int K) {
  __shared__ unsigned short As[128][64];   // 16 KB, XOR-swizzled slots
  __shared__ unsigned short Bs[128][64];   // 16 KB
  const int tid = threadIdx.x;
  const int w = tid >> 6, l = tid & 63;
  const int wm = w >> 1, wn = w & 1;
  const int m0 = blockIdx.y * 128, n0 = blockIdx.x * 128;
  f32x4 acc[4][4];
#pragma unroll
  for (int i = 0; i < 4; ++i)
#pragma unroll
    for (int j = 0; j < 4; ++j) acc[i][j] = (f32x4){0.f, 0.f, 0.f, 0.f};

  for (int k0 = 0; k0 < K; k0 += 64) {
    __syncthreads();                       // prior reads of As/Bs done
#pragma unroll
    for (int j = 0; j < 4; ++j) {          // A: 1024 chunks of 16B
      const int chunk = (w * 4 + j) * 64 + l;
      const int row = chunk >> 3, slot = chunk & 7;
      GLDS16(A + (size_t)(m0 + row) * K + k0 + ((slot ^ (row & 7)) << 3),
             &As[0][0] + (size_t)(w * 4 + j) * 512);
    }
#pragma unroll
    for (int j = 0; j < 4; ++j) {          // B
      const int chunk = (w * 4 + j) * 64 + l;
      const int row = chunk >> 3, slot = chunk & 7;
      GLDS16(Bt + (size_t)(n0 + row) * K + k0 + ((slot ^ (row & 7)) << 3),
             &Bs[0][0] + (size_t)(w * 4 + j) * 512);
    }
    __syncthreads();                       // vmcnt drained by barrier semantics
#pragma unroll
    for (int kk = 0; kk < 2; ++kk) {
      short8 a[4], b[4];
#pragma unroll
      for (int i = 0; i < 4; ++i) {
        const int ar = wm * 64 + i * 16 + (l & 15);
        a[i] = *(const short8*)&As[ar][(((l >> 4) + kk * 4) ^ (ar & 7)) << 3];
        const int br = wn * 64 + i * 16 + (l & 15);
        b[i] = *(const short8*)&Bs[br][(((l >> 4) + kk * 4) ^ (br & 7)) << 3];
      }
#pragma unroll
      for (int mi = 0; mi < 4; ++mi)
#pragma unroll
        for (int ni = 0; ni < 4; ++ni)
          acc[mi][ni] = __builtin_amdgcn_mfma_f32_16x16x32_bf16(
              a[mi], b[ni], acc[mi][ni], 0, 0, 0);
    }
  }
  // ---- epilogue -----------------------------------------------------------
  if (OMODE == 2) {
    unsigned short* vT = (unsigned short*)outp;
#pragma unroll
    for (int mi = 0; mi < 4; ++mi)
#pragma unroll
      for (int ni = 0; ni < 4; ++ni) {
        const int n = n0 + wn * 64 + ni * 16 + (l & 15);
        const int mbase = m0 + wm * 64 + mi * 16 + ((l >> 4) << 2);
        const int bb = mbase >> 11, t = mbase & 2047;
        const float bv = bias[n];
        unsigned short* dst = vT + ((size_t)(bb * 1024 + n)) * Tn + t;
        unsigned int p0 = (unsigned)f2bf(acc[mi][ni][0] + bv) |
                          ((unsigned)f2bf(acc[mi][ni][1] + bv) << 16);
        unsigned int p1 = (unsigned)f2bf(acc[mi][ni][2] + bv) |
                          ((unsigned)f2bf(acc[mi][ni][3] + bv) << 16);
        *(unsigned int*)dst       = p0;
        *(unsigned int*)(dst + 2) = p1;
      }
  } else {
#pragma unroll
    for (int mi = 0; mi < 4; ++mi)
#pragma unroll
      for (int ni = 0; ni < 4; ++ni) {
        const int n = n0 + wn * 64 + ni * 16 + (l & 15);
        const float bv = bias[n];
#pragma unroll
        for (int r = 0; r < 4; ++r) {
          const int m = m0 + wm * 64 + mi * 16 + ((l >> 4) << 2) + r;
          float v = acc[mi][ni][r] + bv;
          if (EPI == 1) v = fmaxf(v, 0.f);
          if (EPI == 2) v += res[(size_t)m * N + n];
          if (OMODE == 1) ((unsigned short*)outp)[(size_t)m * N + n] = f2bf(v);
          else            ((float*)outp)[(size_t)m * N + n] = v;
        }
      }
  }
}

// ---- stage one 64x64 bf16 tile (global row stride grs) into swizzled LDS --
DEVINL void stage64s(unsigned short* lds, const unsigned short* g, int grs,
                     int w, int l) {
#pragma unroll
  for (int j = 0; j < 2; ++j) {
    const int chunk = (w * 2 + j) * 64 + l;
    const int row = chunk >> 3, slot = chunk & 7;
    GLDS16(g + (size_t)row * grs + ((slot ^ (row & 7)) << 3),
           lds + (size_t)(w * 2 + j) * 512);
  }
}

// ---------------- Pass A: column softmax stats (exp2 domain) ----------------
__global__ __launch_bounds__(256)
void colstats_mfma(const unsigned short* __restrict__ qk,
                   float* __restrict__ m2buf, float* __restrict__ rlbuf) {
  __shared__ unsigned short Ks[64][64];
  __shared__ unsigned short Qs[64][64];
  __shared__ float redm[4][4][16], redl[4][4][16];
  const int j0 = blockIdx.x * 64;
  const int bh = blockIdx.y, b = bh >> 4, h = bh & 15;
  const int tid = threadIdx.x, w = tid >> 6, l = tid & 63;
  const unsigned short* kbase = qk + ((size_t)(b * Tn + j0)) * 2048 + 1024 + h * 64;
  const unsigned short* qbase = qk + ((size_t)(b * Tn)) * 2048 + h * 64;
  stage64s(&Ks[0][0], kbase, 2048, w, l);
  float m2[4], ls[4];
#pragma unroll
  for (int ni = 0; ni < 4; ++ni) { m2[ni] = -1e30f; ls[ni] = 0.f; }

  for (int i0 = j0; i0 < Tn; i0 += 64) {
    __syncthreads();
    stage64s(&Qs[0][0], qbase + (size_t)i0 * 2048, 2048, w, l);
    __syncthreads();
    f32x4 s[4];
#pragma unroll
    for (int ni = 0; ni < 4; ++ni) s[ni] = (f32x4){0.f, 0.f, 0.f, 0.f};
#pragma unroll
    for (int kk = 0; kk < 2; ++kk) {
      const int ar = w * 16 + (l & 15);
      const short8 af = *(const short8*)&Qs[ar][(((l >> 4) + kk * 4) ^ (ar & 7)) << 3];
#pragma unroll
      for (int ni = 0; ni < 4; ++ni) {
        const int br = ni * 16 + (l & 15);
        const short8 bfr = *(const short8*)&Ks[br][(((l >> 4) + kk * 4) ^ (br & 7)) << 3];
        s[ni] = __builtin_amdgcn_mfma_f32_16x16x32_bf16(af, bfr, s[ni], 0, 0, 0);
      }
    }
    const bool diag = (i0 == j0);
    const int ib = w * 16 + ((l >> 4) << 2);
#pragma unroll
    for (int ni = 0; ni < 4; ++ni) {
      const int jl = ni * 16 + (l & 15);
      float v0 = s[ni][0] * S2, v1 = s[ni][1] * S2, v2 = s[ni][2] * S2, v3 = s[ni][3] * S2;
      if (!diag) {
        const float tmax = fmaxf(fmaxf(v0, v1), fmaxf(v2, v3));
        const float mn = fmaxf(m2[ni], tmax);
        ls[ni] = ls[ni] * exp2f(m2[ni] - mn) +
                 exp2f(v0 - mn) + exp2f(v1 - mn) + exp2f(v2 - mn) + exp2f(v3 - mn);
        m2[ni] = mn;
      } else {
        const bool g0 = (ib + 0 >= jl), g1 = (ib + 1 >= jl), g2 = (ib + 2 >= jl), g3 = (ib + 3 >= jl);
        const float t0 = g0 ? v0 : -1e30f, t1 = g1 ? v1 : -1e30f;
        const float t2 = g2 ? v2 : -1e30f, t3 = g3 ? v3 : -1e30f;
        const float tmax = fmaxf(fmaxf(t0, t1), fmaxf(t2, t3));
        const float mn = fmaxf(m2[ni], tmax);
        const float e0 = g0 ? exp2f(v0 - mn) : 0.f;
        const float e1 = g1 ? exp2f(v1 - mn) : 0.f;
        const float e2 = g2 ? exp2f(v2 - mn) : 0.f;
        const float e3 = g3 ? exp2f(v3 - mn) : 0.f;
        ls[ni] = ls[ni] * exp2f(m2[ni] - mn) + e0 + e1 + e2 + e3;
        m2[ni] = mn;
      }
    }
  }
  // combine across lane groups (same column j, different row subsets)
#pragma unroll
  for (int ni = 0; ni < 4; ++ni) {
#pragma unroll
    for (int off = 16; off < 64; off <<= 1) {
      const float mo = __shfl_xor(m2[ni], off);
      const float lo = __shfl_xor(ls[ni], off);
      const float mn = fmaxf(m2[ni], mo);
      ls[ni] = ls[ni] * exp2f(m2[ni] - mn) + lo * exp2f(mo - mn);
      m2[ni] = mn;
    }
  }
  if (l < 16) {
#pragma unroll
    for (int ni = 0; ni < 4; ++ni) { redm[w][ni][l] = m2[ni]; redl[w][ni][l] = ls[ni]; }
  }
  __syncthreads();
  if (tid < 64) {
    const int ni = tid >> 4, jl = tid & 15;
    float m = redm[0][ni][jl], sl = redl[0][ni][jl];
#pragma unroll
    for (int wv = 1; wv < 4; ++wv) {
      const float mo = redm[wv][ni][jl], lo = redl[wv][ni][jl];
      const float mn = fmaxf(m, mo);
      sl = sl * exp2f(m - mn) + lo * exp2f(mo - mn);
      m = mn;
    }
    m2buf[(size_t)bh * Tn + j0 + ni * 16 + jl] = m;
    rlbuf[(size_t)bh * Tn + j0 + ni * 16 + jl] = 1.0f / sl;
  }
}

// ---------------- Pass B: att = P * V  (P wave-private via swizzled LDS) ----
__global__ __launch_bounds__(256)
void pv_mfma(const unsigned short* __restrict__ qk,
             const unsigned short* __restrict__ vT,
             const float* __restrict__ m2buf, const float* __restrict__ rlbuf,
             unsigned short* __restrict__ att) {
  __shared__ unsigned short Qs[64][64];
  __shared__ unsigned short Ks[64][64];
  __shared__ unsigned short Vs[64][64];   // [d][j]
  __shared__ unsigned short Ps[64][64];   // [i][j], XOR-swizzled
  __shared__ float m2s[64], rls[64];
  const int i0 = blockIdx.x * 64;
  const int bh = blockIdx.y, b = bh >> 4, h = bh & 15;
  const int tid = threadIdx.x, w = tid >> 6, l = tid & 63;
  const unsigned short* qbase = qk + ((size_t)(b * Tn + i0)) * 2048 + h * 64;
  const unsigned short* kbase = qk + ((size_t)(b * Tn)) * 2048 + 1024 + h * 64;
  const unsigned short* vbase = vT + ((size_t)(b * 1024 + h * 64)) * Tn;
  stage64s(&Qs[0][0], qbase, 2048, w, l);
  f32x4 oacc[4];
#pragma unroll
  for (int ni = 0; ni < 4; ++ni) oacc[ni] = (f32x4){0.f, 0.f, 0.f, 0.f};

  for (int j0 = 0; j0 <= i0; j0 += 64) {
    __syncthreads();
    stage64s(&Ks[0][0], kbase + (size_t)j0 * 2048, 2048, w, l);
#pragma unroll
    for (int j = 0; j < 2; ++j) {          // V tile [d][j], rows are vT rows
      const int chunk = (w * 2 + j) * 64 + l;
      const int row = chunk >> 3, slot = chunk & 7;
      GLDS16(vbase + (size_t)row * Tn + j0 + ((slot ^ (row & 7)) << 3),
             &Vs[0][0] + (size_t)(w * 2 + j) * 512);
    }
    if (tid < 64) {
      m2s[tid] = m2buf[(size_t)bh * Tn + j0 + tid];
      rls[tid] = rlbuf[(size_t)bh * Tn + j0 + tid];
    }
    __syncthreads();
    // S = Q K^T (this wave's 16 rows x 64 cols)
    f32x4 s[4];
#pragma unroll
    for (int ni = 0; ni < 4; ++ni) s[ni] = (f32x4){0.f, 0.f, 0.f, 0.f};
#pragma unroll
    for (int kk = 0; kk < 2; ++kk) {
      const int ar = w * 16 + (l & 15);
      const short8 af = *(const short8*)&Qs[ar][(((l >> 4) + kk * 4) ^ (ar & 7)) << 3];
#pragma unroll
      for (int ni = 0; ni < 4; ++ni) {
        const int br = ni * 16 + (l & 15);
        const short8 bfr = *(const short8*)&Ks[br][(((l >> 4) + kk * 4) ^ (br & 7)) << 3];
        s[ni] = __builtin_amdgcn_mfma_f32_16x16x32_bf16(af, bfr, s[ni], 0, 0, 0);
      }
    }
    // P = exp2(s2 - m2_j) * rl_j  (masked), write to wave-private Ps rows
    const bool diag = (j0 == i0);
    const int ib = w * 16 + ((l >> 4) << 2);
    unsigned short* Pf = &Ps[0][0];
#pragma unroll
    for (int ni = 0; ni < 4; ++ni) {
      const int jl = ni * 16 + (l & 15);
      const float mj = m2s[jl], rj = rls[jl];
#pragma unroll
      for (int r = 0; r < 4; ++r) {
        float p = exp2f(s[ni][r] * S2 - mj) * rj;
        if (diag && (ib + r < jl)) p = 0.f;
        const int il = ib + r;
        Pf[il * 64 + (((jl >> 3) ^ (il & 7)) << 3) + (jl & 7)] = f2bf(p);
      }
    }
    // O += P V   (A = Ps rows i [wave-private], B = Vs rows d)
#pragma unroll
    for (int kk = 0; kk < 2; ++kk) {
      const int ar = w * 16 + (l & 15);
      const short8 pf = *(const short8*)&Ps[ar][(((l >> 4) + kk * 4) ^ (ar & 7)) << 3];
#pragma unroll
      for (int ni = 0; ni < 4; ++ni) {
        const int br = ni * 16 + (l & 15);
        const short8 vf = *(const short8*)&Vs[br][(((l >> 4) + kk * 4) ^ (br & 7)) << 3];
        oacc[ni] = __builtin_amdgcn_mfma_f32_16x16x32_bf16(pf, vf, oacc[ni], 0, 0, 0);
      }
    }
  }
#pragma unroll
  for (int ni = 0; ni < 4; ++ni) {
    const int col = h * 64 + ni * 16 + (l & 15);
#pragma unroll
    for (int r = 0; r < 4; ++r) {
      const int m = b * Tn + i0 + w * 16 + ((l >> 4) << 2) + r;
      att[(size_t)m * 1024 + col] = f2bf(oacc[ni][r]);
    }
  }
}

// ---------------------------------------------------------------------------
extern "C" void kernel_launch(void* const* d_in, const int* in_sizes, int n_in,
                              void* d_out, int out_size, void* d_ws, size_t ws_size,
                              hipStream_t stream) {
  const float* x    = (const float*)d_in[0];
  const float* ln1w = (const float*)d_in[1];
  const float* Wq   = (const float*)d_in[2];
  const float* bq   = (const float*)d_in[3];
  const float* Wk   = (const float*)d_in[4];
  const float* bk   = (const float*)d_in[5];
  const float* Wv   = (const float*)d_in[6];
  const float* bv   = (const float*)d_in[7];
  const float* Wo   = (const float*)d_in[8];
  const float* bo   = (const float*)d_in[9];
  const float* ln2w = (const float*)d_in[10];
  const float* W1   = (const float*)d_in[11];
  const float* b1   = (const float*)d_in[12];
  const float* W2   = (const float*)d_in[13];
  const float* b2   = (const float*)d_in[14];

  uint8_t* wsb = (uint8_t*)d_ws;
  unsigned short* h     = (unsigned short*)(wsb);                    // 8 MB
  unsigned short* qkb   = (unsigned short*)(wsb + (8ull  << 20));    // 16 MB
  unsigned short* vT    = (unsigned short*)(wsb + (24ull << 20));    // 8 MB
  unsigned short* attb  = (unsigned short*)(wsb + (32ull << 20));    // 8 MB
  float*          x1    = (float*)         (wsb + (40ull << 20));    // 16 MB
  unsigned short* ffmid = qkb;   // reuses qkb+vT+attb (32 MB), dead by then
  unsigned short* Wqkt  = (unsigned short*)(wsb + (56ull << 20));    // 4 MB
  unsigned short* Wvt   = (unsigned short*)(wsb + (60ull << 20));    // 2 MB
  unsigned short* Wot   = (unsigned short*)(wsb + (62ull << 20));    // 2 MB
  unsigned short* W1t   = (unsigned short*)(wsb + (64ull << 20));    // 8 MB
  unsigned short* W2t   = (unsigned short*)(wsb + (72ull << 20));    // 8 MB
  float*          biasqk= (float*)         (wsb + (80ull << 20));    // 8 KB
  float*          m2buf = (float*)         (wsb + (81ull << 20));    // 256 KB
  float*          rlbuf = (float*)         (wsb + (81ull << 20) + (256ull << 10));

  // weights -> bf16 B^T
  transpose_cvt<<<dim3(2, 32, 16), 256, 0, stream>>>(Wq, Wqkt,               1024, 64, 65536, 65536);
  transpose_cvt<<<dim3(2, 32, 16), 256, 0, stream>>>(Wk, Wqkt + 1024 * 1024, 1024, 64, 65536, 65536);
  transpose_cvt<<<dim3(2, 32, 16), 256, 0, stream>>>(Wv, Wvt,                1024, 64, 65536, 65536);
  transpose_cvt<<<dim3(32, 32, 1), 256, 0, stream>>>(Wo, Wot,  1024, 1024, 0, 0);
  transpose_cvt<<<dim3(128, 32, 1), 256, 0, stream>>>(W1, W1t, 1024, 4096, 0, 0);
  transpose_cvt<<<dim3(32, 128, 1), 256, 0, stream>>>(W2, W2t, 4096, 1024, 0, 0);
  hipMemcpyAsync(biasqk,        bq, 1024 * sizeof(float), hipMemcpyDeviceToDevice, stream);
  hipMemcpyAsync(biasqk + 1024, bk, 1024 * sizeof(float), hipMemcpyDeviceToDevice, stream);

  // 1. LN1 -> h (bf16)
  ln_bf16<<<Mn, 256, 0, stream>>>(x, ln1w, h);
  // 2. q|k = h @ [Wq;Wk] (N=2048, bf16 out) ; v -> transposed vT
  gemm_bf16<0, 1><<<dim3(16, 32), 256, 0, stream>>>(h, Wqkt, biasqk, nullptr, qkb, Mn, 2048, Cn);
  gemm_bf16<0, 2><<<dim3(8, 32), 256, 0, stream>>>(h, Wvt, bv, nullptr, vT, Mn, 1024, Cn);
  // 3/4. column-softmax attention
  colstats_mfma<<<dim3(Tn / 64, Bn * Hn), 256, 0, stream>>>(qkb, m2buf, rlbuf);
  pv_mfma<<<dim3(Tn / 64, Bn * Hn), 256, 0, stream>>>(qkb, vT, m2buf, rlbuf, attb);
  // 5. x1 = att @ Wo + bo + x  (fp32 out)
  gemm_bf16<2, 0><<<dim3(8, 32), 256, 0, stream>>>(attb, Wot, bo, x, x1, Mn, 1024, Cn);
  // 6. LN2 -> h (bf16)
  ln_bf16<<<Mn, 256, 0, stream>>>(x1, ln2w, h);
  // 7. ffmid = relu(h @ W1 + b1)  (bf16 out)
  gemm_bf16<1, 1><<<dim3(32, 32), 256, 0, stream>>>(h, W1t, b1, nullptr, ffmid, Mn, FFn, Cn);
  // 8. out = ffmid @ W2 + b2 + x1 (fp32 out)
  gemm_bf16<2, 0><<<dim3(8, 32), 256, 0, stream>>>(ffmid, W2t, b2, x1, (float*)d_out, Mn, Cn, FFn);
}